// Round 5
// baseline (1266.566 us; speedup 1.0000x reference)
//
#include <hip/hip_runtime.h>

// MLA prefill: B=2, S=2048, DIM=2048, NH=16, Q_LORA=1536, KV_LORA=512,
// NOPE=128, ROPE=64, VHD=128, QK_HD=192.
// I/O dtype: FP32 (per reference setup_inputs/return). Internal: bf16 MFMA.
//
// WS (bf16 intermediates), high-water 63,963,136 B:
//   qn   @ 0           [4096,1536] bf16  12,582,912
//   kvn  @ 12,582,912  [4096, 576] bf16   4,718,592  (cols 512..575 raw pe)
//   kpe  @ 17,301,504  [4096,  64] bf16     524,288
//   qb   @ 17,825,792  [2048,3072] bf16  12,582,912  (per-batch)
//   kvbb @ 30,408,704  [2048,4096] bf16  16,777,216  (per-batch)
//   ao   @ 47,185,920  [4096,2048] bf16  16,777,216

typedef __bf16 bf16x8 __attribute__((ext_vector_type(8)));
typedef float f32x4 __attribute__((ext_vector_type(4)));
typedef unsigned short u16;

#define SEQ 2048
#define SCALE 0.07216878364870323f  // 192^-0.5
#define NEGBIG -30000.0f            // expf underflows to exactly 0

__device__ __forceinline__ float b2f(u16 u) {
  union { unsigned u; float f; } c; c.u = ((unsigned)u) << 16; return c.f;
}
__device__ __forceinline__ u16 f2b(float f) {  // RNE fp32->bf16
  union { float f; unsigned u; } c; c.f = f;
  unsigned r = (c.u + 0x7fffu + ((c.u >> 16) & 1u)) >> 16;
  return (u16)r;
}

// Stage 8 contiguous elements (bf16 or fp32 source) into LDS as 8 bf16.
template <int F32>
__device__ __forceinline__ void stage8(const void* src, size_t off, u16* dst) {
  if (F32) {
    const float* p = (const float*)src + off;
    float4 a = *(const float4*)p;
    float4 b = *(const float4*)(p + 4);
    union { uint4 v; u16 e[8]; } t;
    t.e[0] = f2b(a.x); t.e[1] = f2b(a.y); t.e[2] = f2b(a.z); t.e[3] = f2b(a.w);
    t.e[4] = f2b(b.x); t.e[5] = f2b(b.y); t.e[6] = f2b(b.z); t.e[7] = f2b(b.w);
    *(uint4*)dst = t.v;
  } else {
    *(uint4*)dst = *(const uint4*)((const u16*)src + off);
  }
}

// ---------------------------------------------------------------------------
// GEMM: out[M,N] = X[M,K] @ W[N,K]^T + bias[N]
// XF/WF: 1 = fp32 source (convert on stage), 0 = bf16 source.
// OF:    1 = fp32 out, 0 = bf16 out. bias is always fp32.
// 128x128 tile, BK=64, 4 waves 2x2, 4x4 16x16x32 bf16 MFMA per wave.
// ---------------------------------------------------------------------------
template <int XF, int WF, int OF>
__global__ __launch_bounds__(256, 2) void gemm_kernel(
    const void* __restrict__ X, int lda, const void* __restrict__ W,
    const float* __restrict__ bias, void* __restrict__ out,
    int M, int N, int K) {
  constexpr int LDT = 72;
  __shared__ alignas(16) u16 As[128 * LDT];
  __shared__ alignas(16) u16 Bs[128 * LDT];
  const int tid = threadIdx.x;
  const int wave = tid >> 6, lane = tid & 63;
  const int quad = lane >> 4, l16 = lane & 15;
  const int bm = blockIdx.x * 128, bn = blockIdx.y * 128;
  const int wm = (wave & 1) * 64, wn = (wave >> 1) * 64;
  const int srow = tid >> 3;           // 0..31
  const int scol = (tid & 7) * 8;      // 0..56

  f32x4 acc[4][4] = {};

  for (int k0 = 0; k0 < K; k0 += 64) {
    __syncthreads();
#pragma unroll
    for (int p = 0; p < 4; ++p) {
      int r = srow + p * 32;
      stage8<XF>(X, (size_t)(bm + r) * lda + k0 + scol, &As[r * LDT + scol]);
      int n = bn + r;
      if (n < N) {
        stage8<WF>(W, (size_t)n * K + k0 + scol, &Bs[r * LDT + scol]);
      } else {
        uint4 z; z.x = z.y = z.z = z.w = 0u;
        *(uint4*)(&Bs[r * LDT + scol]) = z;
      }
    }
    __syncthreads();
#pragma unroll
    for (int kk = 0; kk < 64; kk += 32) {
      bf16x8 a[4], b[4];
#pragma unroll
      for (int i = 0; i < 4; ++i)
        a[i] = *(const bf16x8*)(&As[(wm + i * 16 + l16) * LDT + kk + quad * 8]);
#pragma unroll
      for (int j = 0; j < 4; ++j)
        b[j] = *(const bf16x8*)(&Bs[(wn + j * 16 + l16) * LDT + kk + quad * 8]);
#pragma unroll
      for (int i = 0; i < 4; ++i)
#pragma unroll
        for (int j = 0; j < 4; ++j)
          acc[i][j] = __builtin_amdgcn_mfma_f32_16x16x32_bf16(a[i], b[j], acc[i][j], 0, 0, 0);
    }
  }

#pragma unroll
  for (int i = 0; i < 4; ++i)
#pragma unroll
    for (int j = 0; j < 4; ++j) {
      int col = bn + wn + j * 16 + l16;
      if (col < N) {
        float bv = bias[col];
#pragma unroll
        for (int r = 0; r < 4; ++r) {
          int row = bm + wm + i * 16 + quad * 4 + r;
          float v = acc[i][j][r] + bv;
          if (OF) ((float*)out)[(size_t)row * N + col] = v;
          else    ((u16*)out)[(size_t)row * N + col] = f2b(v);
        }
      }
    }
}

// ---------------------------------------------------------------------------
// RMSNorm in place on bf16: x[row*stride + c], c in [0,C). w is fp32.
// ---------------------------------------------------------------------------
__global__ void rmsnorm_kernel(u16* x, const float* __restrict__ w,
                               int C, int stride) {
  size_t base = (size_t)blockIdx.x * stride;
  float s = 0.f;
  for (int c = threadIdx.x; c < C; c += 256) { float v = b2f(x[base + c]); s += v * v; }
#pragma unroll
  for (int off = 32; off > 0; off >>= 1) s += __shfl_xor(s, off, 64);
  __shared__ float red[4];
  if ((threadIdx.x & 63) == 0) red[threadIdx.x >> 6] = s;
  __syncthreads();
  float tot = red[0] + red[1] + red[2] + red[3];
  float scale = rsqrtf(tot / (float)C + 1e-6f);
  for (int c = threadIdx.x; c < C; c += 256)
    x[base + c] = f2b(b2f(x[base + c]) * scale * w[c]);
}

// ---------------------------------------------------------------------------
// Rope on k_pe: read bf16 kvn cols [512,576), fp32 cos/sin, write bf16 kpe.
// ---------------------------------------------------------------------------
__global__ void rope_kpe_kernel(const u16* __restrict__ kvn,
                                const float* __restrict__ fcos,
                                const float* __restrict__ fsin,
                                u16* __restrict__ kpe) {
  int idx = blockIdx.x * 256 + threadIdx.x;  // token*32 + i
  int t = idx >> 5, i = idx & 31;
  int s = t & (SEQ - 1);
  float c = fcos[s * 32 + i], sn = fsin[s * 32 + i];
  float xr = b2f(kvn[(size_t)t * 576 + 512 + 2 * i]);
  float xi = b2f(kvn[(size_t)t * 576 + 512 + 2 * i + 1]);
  kpe[(size_t)t * 64 + 2 * i]     = f2b(xr * c - xi * sn);
  kpe[(size_t)t * 64 + 2 * i + 1] = f2b(xr * sn + xi * c);
}

// ---------------------------------------------------------------------------
// In-place rope on q_pe for one batch: q[t, h*192 + 128 + 2i], t in [0,2048)
// ---------------------------------------------------------------------------
__global__ void rope_q_kernel(u16* q, const float* __restrict__ fcos,
                              const float* __restrict__ fsin) {
  int idx = blockIdx.x * 256 + threadIdx.x;  // t*512 + h*32 + i
  int t = idx >> 9, h = (idx >> 5) & 15, i = idx & 31;
  float c = fcos[t * 32 + i], sn = fsin[t * 32 + i];
  size_t base = (size_t)t * 3072 + h * 192 + 128 + 2 * i;
  float xr = b2f(q[base]), xi = b2f(q[base + 1]);
  q[base]     = f2b(xr * c - xi * sn);
  q[base + 1] = f2b(xr * sn + xi * c);
}

// ---------------------------------------------------------------------------
// Flash attention (causal), one batch (2048 tokens), one head per blockIdx.y.
// 64 q-rows/block (16/wave), K-tiles of 64. All-bf16 internal.
// ---------------------------------------------------------------------------
__global__ __launch_bounds__(256, 2) void attn_kernel(
    const u16* __restrict__ Q,    // [2048, 3072]
    const u16* __restrict__ KVB,  // [2048, 4096] (k_nope|v per head)
    const u16* __restrict__ KPE,  // [2048, 64]
    u16* __restrict__ O) {        // [2048, 2048]
  constexpr int LK = 200;
  constexpr int LP = 72;
  __shared__ alignas(16) u16 Ks[64 * LK];
  __shared__ alignas(16) u16 Ps[64 * LP];
  __shared__ alignas(16) u16 Vs[128 * LP];

  const int tid = threadIdx.x;
  const int wave = tid >> 6, lane = tid & 63;
  const int quad = lane >> 4, l16 = lane & 15;
  const int q0 = blockIdx.x * 64;
  const int h = blockIdx.y;

  bf16x8 qf[6];
  {
    const u16* qp = Q + (size_t)(q0 + wave * 16 + l16) * 3072 + h * 192 + quad * 8;
#pragma unroll
    for (int c = 0; c < 6; ++c) qf[c] = *(const bf16x8*)(qp + c * 32);
  }

  f32x4 o_acc[8] = {};
  float m_i[4], l_i[4];
#pragma unroll
  for (int r = 0; r < 4; ++r) { m_i[r] = NEGBIG; l_i[r] = 0.f; }

  const int nkt = q0 / 64 + 1;
  for (int kt = 0; kt < nkt; ++kt) {
    const int k0 = kt * 64;
    __syncthreads();
#pragma unroll
    for (int p = 0; p < 6; ++p) {
      int flat = tid + p * 256;
      int r = flat / 24, c8 = (flat % 24) * 8;
      size_t tok = k0 + r;
      uint4 v;
      if (c8 < 128) v = *(const uint4*)(KVB + tok * 4096 + h * 256 + c8);
      else          v = *(const uint4*)(KPE + tok * 64 + (c8 - 128));
      *(uint4*)(&Ks[r * LK + c8]) = v;
    }
#pragma unroll
    for (int p = 0; p < 4; ++p) {
      int flat = tid + p * 256;
      int r = flat / 16, c8 = (flat % 16) * 8;
      size_t tok = k0 + r;
      union { uint4 v4; u16 e[8]; } tmp;
      tmp.v4 = *(const uint4*)(KVB + tok * 4096 + h * 256 + 128 + c8);
#pragma unroll
      for (int j = 0; j < 8; ++j) Vs[(c8 + j) * LP + r] = tmp.e[j];
    }
    __syncthreads();

    f32x4 sc[4];
#pragma unroll
    for (int ni = 0; ni < 4; ++ni) {
      f32x4 a = {};
#pragma unroll
      for (int c = 0; c < 6; ++c) {
        bf16x8 kf = *(const bf16x8*)(&Ks[(ni * 16 + l16) * LK + c * 32 + quad * 8]);
        a = __builtin_amdgcn_mfma_f32_16x16x32_bf16(qf[c], kf, a, 0, 0, 0);
      }
      sc[ni] = a;
    }

    const int qrow_base = q0 + wave * 16 + quad * 4;
    float mloc[4];
#pragma unroll
    for (int r = 0; r < 4; ++r) mloc[r] = NEGBIG;
#pragma unroll
    for (int ni = 0; ni < 4; ++ni) {
      int col = k0 + ni * 16 + l16;
#pragma unroll
      for (int r = 0; r < 4; ++r) {
        float s = sc[ni][r] * SCALE;
        if (col > qrow_base + r) s = NEGBIG;
        sc[ni][r] = s;
        mloc[r] = fmaxf(mloc[r], s);
      }
    }
#pragma unroll
    for (int off = 1; off < 16; off <<= 1)
#pragma unroll
      for (int r = 0; r < 4; ++r) mloc[r] = fmaxf(mloc[r], __shfl_xor(mloc[r], off, 64));

    float alpha[4], rsum[4];
#pragma unroll
    for (int r = 0; r < 4; ++r) {
      float mn = fmaxf(m_i[r], mloc[r]);
      alpha[r] = __expf(m_i[r] - mn);
      m_i[r] = mn;
      rsum[r] = 0.f;
    }
#pragma unroll
    for (int ni = 0; ni < 4; ++ni)
#pragma unroll
      for (int r = 0; r < 4; ++r) {
        float p = __expf(sc[ni][r] - m_i[r]);
        sc[ni][r] = p;
        rsum[r] += p;
      }
#pragma unroll
    for (int off = 1; off < 16; off <<= 1)
#pragma unroll
      for (int r = 0; r < 4; ++r) rsum[r] += __shfl_xor(rsum[r], off, 64);
#pragma unroll
    for (int r = 0; r < 4; ++r) l_i[r] = l_i[r] * alpha[r] + rsum[r];

#pragma unroll
    for (int ni = 0; ni < 4; ++ni)
#pragma unroll
      for (int r = 0; r < 4; ++r)
        Ps[(wave * 16 + quad * 4 + r) * LP + ni * 16 + l16] = f2b(sc[ni][r]);

    __syncthreads();  // fence: u16 P-writes ordered before bf16x8 P-reads

#pragma unroll
    for (int t8 = 0; t8 < 8; ++t8)
#pragma unroll
      for (int r = 0; r < 4; ++r) o_acc[t8][r] *= alpha[r];

    bf16x8 pf0 = *(const bf16x8*)(&Ps[(wave * 16 + l16) * LP + quad * 8]);
    bf16x8 pf1 = *(const bf16x8*)(&Ps[(wave * 16 + l16) * LP + 32 + quad * 8]);
#pragma unroll
    for (int ni = 0; ni < 8; ++ni) {
      bf16x8 vf0 = *(const bf16x8*)(&Vs[(ni * 16 + l16) * LP + quad * 8]);
      bf16x8 vf1 = *(const bf16x8*)(&Vs[(ni * 16 + l16) * LP + 32 + quad * 8]);
      o_acc[ni] = __builtin_amdgcn_mfma_f32_16x16x32_bf16(pf0, vf0, o_acc[ni], 0, 0, 0);
      o_acc[ni] = __builtin_amdgcn_mfma_f32_16x16x32_bf16(pf1, vf1, o_acc[ni], 0, 0, 0);
    }
  }

#pragma unroll
  for (int ni = 0; ni < 8; ++ni) {
    int col = h * 128 + ni * 16 + l16;
#pragma unroll
    for (int r = 0; r < 4; ++r) {
      size_t row = q0 + wave * 16 + quad * 4 + r;
      O[row * 2048 + col] = f2b(o_acc[ni][r] / l_i[r]);
    }
  }
}

// ---------------------------------------------------------------------------
extern "C" void kernel_launch(void* const* d_in, const int* in_sizes, int n_in,
                              void* d_out, int out_size, void* d_ws, size_t ws_size,
                              hipStream_t stream) {
  const float* x      = (const float*)d_in[0];
  const float* fcos   = (const float*)d_in[1];
  const float* fsin   = (const float*)d_in[2];
  const float* wqa    = (const float*)d_in[3];
  const float* wqa_b  = (const float*)d_in[4];
  const float* qnw    = (const float*)d_in[5];
  const float* wqb    = (const float*)d_in[6];
  const float* wqb_b  = (const float*)d_in[7];
  const float* wkva   = (const float*)d_in[8];
  const float* wkva_b = (const float*)d_in[9];
  const float* kvnw   = (const float*)d_in[10];
  const float* wkvb   = (const float*)d_in[11];
  const float* wkvb_b = (const float*)d_in[12];
  const float* wo     = (const float*)d_in[13];
  const float* wo_b   = (const float*)d_in[14];

  char* ws = (char*)d_ws;
  u16* qn   = (u16*)(ws + 0);           // [4096,1536]
  u16* kvn  = (u16*)(ws + 12582912);    // [4096,576]
  u16* kpe  = (u16*)(ws + 17301504);    // [4096,64]
  u16* qb   = (u16*)(ws + 17825792);    // [2048,3072] per-batch
  u16* kvbb = (u16*)(ws + 30408704);    // [2048,4096] per-batch
  u16* ao   = (u16*)(ws + 47185920);    // [4096,2048]

  dim3 blk(256);
  // x(f32) @ wqa(f32)^T -> qn(bf16)
  gemm_kernel<1,1,0><<<dim3(32, 12), blk, 0, stream>>>(x, 2048, wqa, wqa_b, qn, 4096, 1536, 2048);
  // x(f32) @ wkva(f32)^T -> kvn(bf16)
  gemm_kernel<1,1,0><<<dim3(32, 5),  blk, 0, stream>>>(x, 2048, wkva, wkva_b, kvn, 4096, 576, 2048);
  rmsnorm_kernel<<<4096, blk, 0, stream>>>(qn, qnw, 1536, 1536);
  rmsnorm_kernel<<<4096, blk, 0, stream>>>(kvn, kvnw, 512, 576);
  rope_kpe_kernel<<<512, blk, 0, stream>>>(kvn, fcos, fsin, kpe);

  for (int b = 0; b < 2; ++b) {
    const u16* qn_b  = qn  + (size_t)b * 2048 * 1536;
    const u16* kvn_b = kvn + (size_t)b * 2048 * 576;
    const u16* kpe_b = kpe + (size_t)b * 2048 * 64;
    u16* ao_b        = ao  + (size_t)b * 2048 * 2048;
    // qn(bf16) @ wqb(f32)^T -> qb(bf16)
    gemm_kernel<0,1,0><<<dim3(16, 24), blk, 0, stream>>>(qn_b, 1536, wqb, wqb_b, qb, 2048, 3072, 1536);
    rope_q_kernel<<<4096, blk, 0, stream>>>(qb, fcos, fsin);
    // kvn(bf16) @ wkvb(f32)^T -> kvbb(bf16)
    gemm_kernel<0,1,0><<<dim3(16, 32), blk, 0, stream>>>(kvn_b, 576, wkvb, wkvb_b, kvbb, 2048, 4096, 512);
    attn_kernel<<<dim3(32, 16), blk, 0, stream>>>(qb, kvbb, kpe_b, ao_b);
  }

  // ao(bf16) @ wo(f32)^T -> d_out(f32)
  gemm_kernel<0,1,1><<<dim3(32, 16), blk, 0, stream>>>(ao, 2048, wo, wo_b, (float*)d_out, 4096, 2048, 2048);
}

// Round 6
// 1225.620 us; speedup vs baseline: 1.0334x; 1.0334x over previous
//
#include <hip/hip_runtime.h>

// MLA prefill: B=2, S=2048, DIM=2048, NH=16, Q_LORA=1536, KV_LORA=512,
// NOPE=128, ROPE=64, VHD=128, QK_HD=192.
// I/O dtype: FP32. Internal: bf16 MFMA.
//
// WS (bf16 intermediates), high-water 63,963,136 B:
//   qn   @ 0           [4096,1536]
//   kvn  @ 12,582,912  [4096, 576]  (cols 512..575 raw pe)
//   kpe  @ 17,301,504  [4096,  64]
//   qb   @ 17,825,792  [2048,3072]  (per-batch, pre-scaled by SCALE)
//   kvbb @ 30,408,704  [2048,4096]  (per-batch)
//   ao   @ 47,185,920  [4096,2048]

typedef __bf16 bf16x8 __attribute__((ext_vector_type(8)));
typedef float f32x4 __attribute__((ext_vector_type(4)));
typedef unsigned short u16;

#define SEQ 2048
#define SCALE 0.07216878364870323f  // 192^-0.5
#define NEGBIG -30000.0f            // expf underflows to exactly 0

__device__ __forceinline__ float b2f(u16 u) {
  union { unsigned u; float f; } c; c.u = ((unsigned)u) << 16; return c.f;
}
__device__ __forceinline__ u16 f2b(float f) {  // RNE fp32->bf16
  union { float f; unsigned u; } c; c.f = f;
  unsigned r = (c.u + 0x7fffu + ((c.u >> 16) & 1u)) >> 16;
  return (u16)r;
}

// Stage 8 contiguous elements (bf16 or fp32 source) into LDS as 8 bf16.
template <int F32>
__device__ __forceinline__ void stage8(const void* src, size_t off, u16* dst) {
  if (F32) {
    const float* p = (const float*)src + off;
    float4 a = *(const float4*)p;
    float4 b = *(const float4*)(p + 4);
    union { uint4 v; u16 e[8]; } t;
    t.e[0] = f2b(a.x); t.e[1] = f2b(a.y); t.e[2] = f2b(a.z); t.e[3] = f2b(a.w);
    t.e[4] = f2b(b.x); t.e[5] = f2b(b.y); t.e[6] = f2b(b.z); t.e[7] = f2b(b.w);
    *(uint4*)dst = t.v;
  } else {
    *(uint4*)dst = *(const uint4*)((const u16*)src + off);
  }
}

// ---------------------------------------------------------------------------
// GEMM: out[M,N] = (X[M,K] @ W[N,K]^T + bias[N]) * oscale
// XF/WF: 1 = fp32 source (convert on stage), 0 = bf16. OF: 1 = fp32 out.
// 128x128 tile, BK=64, 4 waves 2x2, 4x4 16x16x32 bf16 MFMA per wave.
// ---------------------------------------------------------------------------
template <int XF, int WF, int OF>
__global__ __launch_bounds__(256, 2) void gemm_kernel(
    const void* __restrict__ X, int lda, const void* __restrict__ W,
    const float* __restrict__ bias, void* __restrict__ out,
    int M, int N, int K, float oscale) {
  constexpr int LDT = 72;
  __shared__ alignas(16) u16 As[128 * LDT];
  __shared__ alignas(16) u16 Bs[128 * LDT];
  const int tid = threadIdx.x;
  const int wave = tid >> 6, lane = tid & 63;
  const int quad = lane >> 4, l16 = lane & 15;
  const int bm = blockIdx.x * 128, bn = blockIdx.y * 128;
  const int wm = (wave & 1) * 64, wn = (wave >> 1) * 64;
  const int srow = tid >> 3;           // 0..31
  const int scol = (tid & 7) * 8;      // 0..56

  f32x4 acc[4][4] = {};

  for (int k0 = 0; k0 < K; k0 += 64) {
    __syncthreads();
#pragma unroll
    for (int p = 0; p < 4; ++p) {
      int r = srow + p * 32;
      stage8<XF>(X, (size_t)(bm + r) * lda + k0 + scol, &As[r * LDT + scol]);
      int n = bn + r;
      if (n < N) {
        stage8<WF>(W, (size_t)n * K + k0 + scol, &Bs[r * LDT + scol]);
      } else {
        uint4 z; z.x = z.y = z.z = z.w = 0u;
        *(uint4*)(&Bs[r * LDT + scol]) = z;
      }
    }
    __syncthreads();
#pragma unroll
    for (int kk = 0; kk < 64; kk += 32) {
      bf16x8 a[4], b[4];
#pragma unroll
      for (int i = 0; i < 4; ++i)
        a[i] = *(const bf16x8*)(&As[(wm + i * 16 + l16) * LDT + kk + quad * 8]);
#pragma unroll
      for (int j = 0; j < 4; ++j)
        b[j] = *(const bf16x8*)(&Bs[(wn + j * 16 + l16) * LDT + kk + quad * 8]);
#pragma unroll
      for (int i = 0; i < 4; ++i)
#pragma unroll
        for (int j = 0; j < 4; ++j)
          acc[i][j] = __builtin_amdgcn_mfma_f32_16x16x32_bf16(a[i], b[j], acc[i][j], 0, 0, 0);
    }
  }

#pragma unroll
  for (int i = 0; i < 4; ++i)
#pragma unroll
    for (int j = 0; j < 4; ++j) {
      int col = bn + wn + j * 16 + l16;
      if (col < N) {
        float bv = bias[col];
#pragma unroll
        for (int r = 0; r < 4; ++r) {
          int row = bm + wm + i * 16 + quad * 4 + r;
          float v = (acc[i][j][r] + bv) * oscale;
          if (OF) ((float*)out)[(size_t)row * N + col] = v;
          else    ((u16*)out)[(size_t)row * N + col] = f2b(v);
        }
      }
    }
}

// ---------------------------------------------------------------------------
__global__ void rmsnorm_kernel(u16* x, const float* __restrict__ w,
                               int C, int stride) {
  size_t base = (size_t)blockIdx.x * stride;
  float s = 0.f;
  for (int c = threadIdx.x; c < C; c += 256) { float v = b2f(x[base + c]); s += v * v; }
#pragma unroll
  for (int off = 32; off > 0; off >>= 1) s += __shfl_xor(s, off, 64);
  __shared__ float red[4];
  if ((threadIdx.x & 63) == 0) red[threadIdx.x >> 6] = s;
  __syncthreads();
  float tot = red[0] + red[1] + red[2] + red[3];
  float scale = rsqrtf(tot / (float)C + 1e-6f);
  for (int c = threadIdx.x; c < C; c += 256)
    x[base + c] = f2b(b2f(x[base + c]) * scale * w[c]);
}

// ---------------------------------------------------------------------------
__global__ void rope_kpe_kernel(const u16* __restrict__ kvn,
                                const float* __restrict__ fcos,
                                const float* __restrict__ fsin,
                                u16* __restrict__ kpe) {
  int idx = blockIdx.x * 256 + threadIdx.x;  // token*32 + i
  int t = idx >> 5, i = idx & 31;
  int s = t & (SEQ - 1);
  float c = fcos[s * 32 + i], sn = fsin[s * 32 + i];
  float xr = b2f(kvn[(size_t)t * 576 + 512 + 2 * i]);
  float xi = b2f(kvn[(size_t)t * 576 + 512 + 2 * i + 1]);
  kpe[(size_t)t * 64 + 2 * i]     = f2b(xr * c - xi * sn);
  kpe[(size_t)t * 64 + 2 * i + 1] = f2b(xr * sn + xi * c);
}

// ---------------------------------------------------------------------------
__global__ void rope_q_kernel(u16* q, const float* __restrict__ fcos,
                              const float* __restrict__ fsin) {
  int idx = blockIdx.x * 256 + threadIdx.x;  // t*512 + h*32 + i
  int t = idx >> 9, h = (idx >> 5) & 15, i = idx & 31;
  float c = fcos[t * 32 + i], sn = fsin[t * 32 + i];
  size_t base = (size_t)t * 3072 + h * 192 + 128 + 2 * i;
  float xr = b2f(q[base]), xi = b2f(q[base + 1]);
  q[base]     = f2b(xr * c - xi * sn);
  q[base + 1] = f2b(xr * sn + xi * c);
}

// ---------------------------------------------------------------------------
// Flash attention (causal), one batch, one head per blockIdx.y.
// 64 q-rows/block (16/wave), K-tiles of 64.
// Round-6 changes: (1) XOR-swizzled V^T staging — kills the 16-way bank
// conflict (was 24% of CU-cycles); (2) register prefetch of next K/V tile
// (global latency hidden behind compute); (3) causal mask only on the
// diagonal tile; (4) SCALE pre-folded into Q (gemm epilogue).
// ---------------------------------------------------------------------------
__global__ __launch_bounds__(256, 2) void attn_kernel(
    const u16* __restrict__ Q,    // [2048, 3072] (pre-scaled by SCALE)
    const u16* __restrict__ KVB,  // [2048, 4096] (k_nope|v per head)
    const u16* __restrict__ KPE,  // [2048, 64]
    u16* __restrict__ O) {        // [2048, 2048]
  constexpr int LK = 200;
  constexpr int LP = 72;
  __shared__ alignas(16) u16 Ks[64 * LK];
  __shared__ alignas(16) u16 Ps[64 * LP];
  __shared__ alignas(16) u16 Vs[128 * LP];  // swizzled V^T

  const int tid = threadIdx.x;
  const int wave = tid >> 6, lane = tid & 63;
  const int quad = lane >> 4, l16 = lane & 15;
  const int q0 = blockIdx.x * 64;
  const int h = blockIdx.y;

  bf16x8 qf[6];
  {
    const u16* qp = Q + (size_t)(q0 + wave * 16 + l16) * 3072 + h * 192 + quad * 8;
#pragma unroll
    for (int c = 0; c < 6; ++c) qf[c] = *(const bf16x8*)(qp + c * 32);
  }

  f32x4 o_acc[8] = {};
  float m_i[4], l_i[4];
#pragma unroll
  for (int r = 0; r < 4; ++r) { m_i[r] = NEGBIG; l_i[r] = 0.f; }

  const int nkt = q0 / 64 + 1;

  // ---- register prefetch buffers (tile t+1 global->VGPR) ----
  uint4 kreg[6], vreg[4];
  auto load_tile = [&](int kt) {
    int k0 = kt * 64;
#pragma unroll
    for (int p = 0; p < 6; ++p) {
      int flat = tid + p * 256;
      int r = flat / 24, c8 = (flat % 24) * 8;
      const u16* src = (c8 < 128)
          ? (KVB + (size_t)(k0 + r) * 4096 + h * 256 + c8)
          : (KPE + (size_t)(k0 + r) * 64 + (c8 - 128));
      kreg[p] = *(const uint4*)src;
    }
#pragma unroll
    for (int p = 0; p < 4; ++p) {
      int flat = tid + p * 256;
      int r = flat / 16, c8 = (flat % 16) * 8;
      vreg[p] = *(const uint4*)(KVB + (size_t)(k0 + r) * 4096 + h * 256 + 128 + c8);
    }
  };

  load_tile(0);
  for (int kt = 0; kt < nkt; ++kt) {
    const int k0 = kt * 64;
    __syncthreads();  // previous iteration's LDS readers done
    // regs -> LDS
#pragma unroll
    for (int p = 0; p < 6; ++p) {
      int flat = tid + p * 256;
      int r = flat / 24, c8 = (flat % 24) * 8;
      *(uint4*)(&Ks[r * LK + c8]) = kreg[p];
    }
#pragma unroll
    for (int p = 0; p < 4; ++p) {
      int flat = tid + p * 256;
      int r = flat / 16, c8 = (flat % 16) * 8;
      union { uint4 v4; u16 e[8]; } t;
      t.v4 = vreg[p];
      int rs = r >> 3, rl = r & 7;
#pragma unroll
      for (int j = 0; j < 8; ++j) {
        int n = c8 + j;
        Vs[n * LP + ((rs ^ ((n >> 3) & 7)) << 3) + rl] = t.e[j];
      }
    }
    __syncthreads();
    if (kt + 1 < nkt) load_tile(kt + 1);  // latency hidden by compute below

    // scores: 16(q) x 64(k) per wave (Q pre-scaled)
    f32x4 sc[4];
#pragma unroll
    for (int ni = 0; ni < 4; ++ni) {
      f32x4 a = {};
#pragma unroll
      for (int c = 0; c < 6; ++c) {
        bf16x8 kf = *(const bf16x8*)(&Ks[(ni * 16 + l16) * LK + c * 32 + quad * 8]);
        a = __builtin_amdgcn_mfma_f32_16x16x32_bf16(qf[c], kf, a, 0, 0, 0);
      }
      sc[ni] = a;
    }

    const int qrow_base = q0 + wave * 16 + quad * 4;
    if (kt == nkt - 1) {  // only the diagonal tile needs the causal mask
#pragma unroll
      for (int ni = 0; ni < 4; ++ni) {
        int col = k0 + ni * 16 + l16;
#pragma unroll
        for (int r = 0; r < 4; ++r)
          if (col > qrow_base + r) sc[ni][r] = NEGBIG;
      }
    }

    float mloc[4];
#pragma unroll
    for (int r = 0; r < 4; ++r) mloc[r] = NEGBIG;
#pragma unroll
    for (int ni = 0; ni < 4; ++ni)
#pragma unroll
      for (int r = 0; r < 4; ++r) mloc[r] = fmaxf(mloc[r], sc[ni][r]);
#pragma unroll
    for (int off = 1; off < 16; off <<= 1)
#pragma unroll
      for (int r = 0; r < 4; ++r) mloc[r] = fmaxf(mloc[r], __shfl_xor(mloc[r], off, 64));

    float alpha[4], rsum[4];
#pragma unroll
    for (int r = 0; r < 4; ++r) {
      float mn = fmaxf(m_i[r], mloc[r]);
      alpha[r] = __expf(m_i[r] - mn);
      m_i[r] = mn;
      rsum[r] = 0.f;
    }
#pragma unroll
    for (int ni = 0; ni < 4; ++ni)
#pragma unroll
      for (int r = 0; r < 4; ++r) {
        float p = __expf(sc[ni][r] - m_i[r]);
        sc[ni][r] = p;
        rsum[r] += p;
      }
#pragma unroll
    for (int off = 1; off < 16; off <<= 1)
#pragma unroll
      for (int r = 0; r < 4; ++r) rsum[r] += __shfl_xor(rsum[r], off, 64);
#pragma unroll
    for (int r = 0; r < 4; ++r) l_i[r] = l_i[r] * alpha[r] + rsum[r];

#pragma unroll
    for (int ni = 0; ni < 4; ++ni)
#pragma unroll
      for (int r = 0; r < 4; ++r)
        Ps[(wave * 16 + quad * 4 + r) * LP + ni * 16 + l16] = f2b(sc[ni][r]);

    __syncthreads();  // fence: u16 P-writes ordered before bf16x8 P-reads

#pragma unroll
    for (int t8 = 0; t8 < 8; ++t8)
#pragma unroll
      for (int r = 0; r < 4; ++r) o_acc[t8][r] *= alpha[r];

    bf16x8 pf0 = *(const bf16x8*)(&Ps[(wave * 16 + l16) * LP + quad * 8]);
    bf16x8 pf1 = *(const bf16x8*)(&Ps[(wave * 16 + l16) * LP + 32 + quad * 8]);
#pragma unroll
    for (int ni = 0; ni < 8; ++ni) {
      int n0 = ni * 16 + l16;
      int sw = (n0 >> 3) & 7;
      bf16x8 vf0 = *(const bf16x8*)(&Vs[n0 * LP + ((quad ^ sw) << 3)]);
      bf16x8 vf1 = *(const bf16x8*)(&Vs[n0 * LP + (((4 + quad) ^ sw) << 3)]);
      o_acc[ni] = __builtin_amdgcn_mfma_f32_16x16x32_bf16(pf0, vf0, o_acc[ni], 0, 0, 0);
      o_acc[ni] = __builtin_amdgcn_mfma_f32_16x16x32_bf16(pf1, vf1, o_acc[ni], 0, 0, 0);
    }
  }

#pragma unroll
  for (int ni = 0; ni < 8; ++ni) {
    int col = h * 128 + ni * 16 + l16;
#pragma unroll
    for (int r = 0; r < 4; ++r) {
      size_t row = q0 + wave * 16 + quad * 4 + r;
      O[row * 2048 + col] = f2b(o_acc[ni][r] / l_i[r]);
    }
  }
}

// ---------------------------------------------------------------------------
extern "C" void kernel_launch(void* const* d_in, const int* in_sizes, int n_in,
                              void* d_out, int out_size, void* d_ws, size_t ws_size,
                              hipStream_t stream) {
  const float* x      = (const float*)d_in[0];
  const float* fcos   = (const float*)d_in[1];
  const float* fsin   = (const float*)d_in[2];
  const float* wqa    = (const float*)d_in[3];
  const float* wqa_b  = (const float*)d_in[4];
  const float* qnw    = (const float*)d_in[5];
  const float* wqb    = (const float*)d_in[6];
  const float* wqb_b  = (const float*)d_in[7];
  const float* wkva   = (const float*)d_in[8];
  const float* wkva_b = (const float*)d_in[9];
  const float* kvnw   = (const float*)d_in[10];
  const float* wkvb   = (const float*)d_in[11];
  const float* wkvb_b = (const float*)d_in[12];
  const float* wo     = (const float*)d_in[13];
  const float* wo_b   = (const float*)d_in[14];

  char* ws = (char*)d_ws;
  u16* qn   = (u16*)(ws + 0);           // [4096,1536]
  u16* kvn  = (u16*)(ws + 12582912);    // [4096,576]
  u16* kpe  = (u16*)(ws + 17301504);    // [4096,64]
  u16* qb   = (u16*)(ws + 17825792);    // [2048,3072] per-batch
  u16* kvbb = (u16*)(ws + 30408704);    // [2048,4096] per-batch
  u16* ao   = (u16*)(ws + 47185920);    // [4096,2048]

  dim3 blk(256);
  gemm_kernel<1,1,0><<<dim3(32, 12), blk, 0, stream>>>(x, 2048, wqa, wqa_b, qn, 4096, 1536, 2048, 1.0f);
  gemm_kernel<1,1,0><<<dim3(32, 5),  blk, 0, stream>>>(x, 2048, wkva, wkva_b, kvn, 4096, 576, 2048, 1.0f);
  rmsnorm_kernel<<<4096, blk, 0, stream>>>(qn, qnw, 1536, 1536);
  rmsnorm_kernel<<<4096, blk, 0, stream>>>(kvn, kvnw, 512, 576);
  rope_kpe_kernel<<<512, blk, 0, stream>>>(kvn, fcos, fsin, kpe);

  for (int b = 0; b < 2; ++b) {
    const u16* qn_b  = qn  + (size_t)b * 2048 * 1536;
    const u16* kvn_b = kvn + (size_t)b * 2048 * 576;
    const u16* kpe_b = kpe + (size_t)b * 2048 * 64;
    u16* ao_b        = ao  + (size_t)b * 2048 * 2048;
    // q projection with SCALE folded into the epilogue (rope is linear)
    gemm_kernel<0,1,0><<<dim3(16, 24), blk, 0, stream>>>(qn_b, 1536, wqb, wqb_b, qb, 2048, 3072, 1536, SCALE);
    rope_q_kernel<<<4096, blk, 0, stream>>>(qb, fcos, fsin);
    gemm_kernel<0,1,0><<<dim3(16, 32), blk, 0, stream>>>(kvn_b, 576, wkvb, wkvb_b, kvbb, 2048, 4096, 512, 1.0f);
    attn_kernel<<<dim3(32, 16), blk, 0, stream>>>(qb, kvbb, kpe_b, ao_b);
  }

  gemm_kernel<0,1,1><<<dim3(32, 16), blk, 0, stream>>>(ao, 2048, wo, wo_b, (float*)d_out, 4096, 2048, 2048, 1.0f);
}

// Round 7
// 1024.212 us; speedup vs baseline: 1.2366x; 1.1966x over previous
//
#include <hip/hip_runtime.h>

// MLA prefill: B=2, S=2048, DIM=2048, NH=16, Q_LORA=1536, KV_LORA=512,
// NOPE=128, ROPE=64, VHD=128, QK_HD=192.
// I/O dtype: FP32. Internal: bf16 MFMA.
//
// Head-group split (8 heads/pass) so BOTH batches fit in one attn launch:
// WS high-water 63,963,136 B:
//   qn   @ 0           [4096,1536]
//   kvn  @ 12,582,912  [4096, 576]  (cols 512..575 raw pe)
//   kpe  @ 17,301,504  [4096,  64]
//   qb   @ 17,825,792  [4096,1536]  (8 heads x 192, pre-scaled by SCALE)
//   kvbb @ 30,408,704  [4096,2048]  (8 heads x (k_nope128|v128))
//   ao   @ 47,185,920  [4096,2048]

typedef __bf16 bf16x8 __attribute__((ext_vector_type(8)));
typedef float f32x4 __attribute__((ext_vector_type(4)));
typedef unsigned short u16;

#define SEQ 2048
#define SCALE 0.07216878364870323f  // 192^-0.5
#define NEGBIG -30000.0f            // expf underflows to exactly 0

__device__ __forceinline__ float b2f(u16 u) {
  union { unsigned u; float f; } c; c.u = ((unsigned)u) << 16; return c.f;
}
__device__ __forceinline__ u16 f2b(float f) {  // RNE fp32->bf16
  union { float f; unsigned u; } c; c.f = f;
  unsigned r = (c.u + 0x7fffu + ((c.u >> 16) & 1u)) >> 16;
  return (u16)r;
}

// Stage 8 contiguous elements (bf16 or fp32 source) into LDS as 8 bf16.
template <int F32>
__device__ __forceinline__ void stage8(const void* src, size_t off, u16* dst) {
  if (F32) {
    const float* p = (const float*)src + off;
    float4 a = *(const float4*)p;
    float4 b = *(const float4*)(p + 4);
    union { uint4 v; u16 e[8]; } t;
    t.e[0] = f2b(a.x); t.e[1] = f2b(a.y); t.e[2] = f2b(a.z); t.e[3] = f2b(a.w);
    t.e[4] = f2b(b.x); t.e[5] = f2b(b.y); t.e[6] = f2b(b.z); t.e[7] = f2b(b.w);
    *(uint4*)dst = t.v;
  } else {
    *(uint4*)dst = *(const uint4*)((const u16*)src + off);
  }
}

// ---------------------------------------------------------------------------
// GEMM: out[M,N] = (X[M,K] @ W[N,K]^T + bias[N]) * oscale
// XF/WF: 1 = fp32 source (convert on stage), 0 = bf16. OF: 1 = fp32 out.
// 128x128 tile, BK=64, 4 waves 2x2, 4x4 16x16x32 bf16 MFMA per wave.
// ---------------------------------------------------------------------------
template <int XF, int WF, int OF>
__global__ __launch_bounds__(256, 2) void gemm_kernel(
    const void* __restrict__ X, int lda, const void* __restrict__ W,
    const float* __restrict__ bias, void* __restrict__ out,
    int M, int N, int K, float oscale) {
  constexpr int LDT = 72;
  __shared__ alignas(16) u16 As[128 * LDT];
  __shared__ alignas(16) u16 Bs[128 * LDT];
  const int tid = threadIdx.x;
  const int wave = tid >> 6, lane = tid & 63;
  const int quad = lane >> 4, l16 = lane & 15;
  const int bm = blockIdx.x * 128, bn = blockIdx.y * 128;
  const int wm = (wave & 1) * 64, wn = (wave >> 1) * 64;
  const int srow = tid >> 3;           // 0..31
  const int scol = (tid & 7) * 8;      // 0..56

  f32x4 acc[4][4] = {};

  for (int k0 = 0; k0 < K; k0 += 64) {
    __syncthreads();
#pragma unroll
    for (int p = 0; p < 4; ++p) {
      int r = srow + p * 32;
      stage8<XF>(X, (size_t)(bm + r) * lda + k0 + scol, &As[r * LDT + scol]);
      int n = bn + r;
      if (n < N) {
        stage8<WF>(W, (size_t)n * K + k0 + scol, &Bs[r * LDT + scol]);
      } else {
        uint4 z; z.x = z.y = z.z = z.w = 0u;
        *(uint4*)(&Bs[r * LDT + scol]) = z;
      }
    }
    __syncthreads();
#pragma unroll
    for (int kk = 0; kk < 64; kk += 32) {
      bf16x8 a[4], b[4];
#pragma unroll
      for (int i = 0; i < 4; ++i)
        a[i] = *(const bf16x8*)(&As[(wm + i * 16 + l16) * LDT + kk + quad * 8]);
#pragma unroll
      for (int j = 0; j < 4; ++j)
        b[j] = *(const bf16x8*)(&Bs[(wn + j * 16 + l16) * LDT + kk + quad * 8]);
#pragma unroll
      for (int i = 0; i < 4; ++i)
#pragma unroll
        for (int j = 0; j < 4; ++j)
          acc[i][j] = __builtin_amdgcn_mfma_f32_16x16x32_bf16(a[i], b[j], acc[i][j], 0, 0, 0);
    }
  }

#pragma unroll
  for (int i = 0; i < 4; ++i)
#pragma unroll
    for (int j = 0; j < 4; ++j) {
      int col = bn + wn + j * 16 + l16;
      if (col < N) {
        float bv = bias[col];
#pragma unroll
        for (int r = 0; r < 4; ++r) {
          int row = bm + wm + i * 16 + quad * 4 + r;
          float v = (acc[i][j][r] + bv) * oscale;
          if (OF) ((float*)out)[(size_t)row * N + col] = v;
          else    ((u16*)out)[(size_t)row * N + col] = f2b(v);
        }
      }
    }
}

// ---------------------------------------------------------------------------
__global__ void rmsnorm_kernel(u16* x, const float* __restrict__ w,
                               int C, int stride) {
  size_t base = (size_t)blockIdx.x * stride;
  float s = 0.f;
  for (int c = threadIdx.x; c < C; c += 256) { float v = b2f(x[base + c]); s += v * v; }
#pragma unroll
  for (int off = 32; off > 0; off >>= 1) s += __shfl_xor(s, off, 64);
  __shared__ float red[4];
  if ((threadIdx.x & 63) == 0) red[threadIdx.x >> 6] = s;
  __syncthreads();
  float tot = red[0] + red[1] + red[2] + red[3];
  float scale = rsqrtf(tot / (float)C + 1e-6f);
  for (int c = threadIdx.x; c < C; c += 256)
    x[base + c] = f2b(b2f(x[base + c]) * scale * w[c]);
}

// ---------------------------------------------------------------------------
__global__ void rope_kpe_kernel(const u16* __restrict__ kvn,
                                const float* __restrict__ fcos,
                                const float* __restrict__ fsin,
                                u16* __restrict__ kpe) {
  int idx = blockIdx.x * 256 + threadIdx.x;  // token*32 + i
  int t = idx >> 5, i = idx & 31;
  int s = t & (SEQ - 1);
  float c = fcos[s * 32 + i], sn = fsin[s * 32 + i];
  float xr = b2f(kvn[(size_t)t * 576 + 512 + 2 * i]);
  float xi = b2f(kvn[(size_t)t * 576 + 512 + 2 * i + 1]);
  kpe[(size_t)t * 64 + 2 * i]     = f2b(xr * c - xi * sn);
  kpe[(size_t)t * 64 + 2 * i + 1] = f2b(xr * sn + xi * c);
}

// ---------------------------------------------------------------------------
// In-place rope on q_pe, qb layout [4096 tokens, 8 heads x 192].
// ---------------------------------------------------------------------------
__global__ void rope_q_kernel(u16* q, const float* __restrict__ fcos,
                              const float* __restrict__ fsin) {
  int idx = blockIdx.x * 256 + threadIdx.x;  // t*256 + h*32 + i
  int t = idx >> 8, h = (idx >> 5) & 7, i = idx & 31;
  int s = t & (SEQ - 1);
  float c = fcos[s * 32 + i], sn = fsin[s * 32 + i];
  size_t base = (size_t)t * 1536 + h * 192 + 128 + 2 * i;
  float xr = b2f(q[base]), xi = b2f(q[base + 1]);
  q[base]     = f2b(xr * c - xi * sn);
  q[base + 1] = f2b(xr * sn + xi * c);
}

// ---------------------------------------------------------------------------
// Flash attention (causal). grid (16 pairs, 8 heads, 2 batches) — block i
// processes q-tiles i and 31-i (uniform 33 K-tile iters/block → perfect
// balance, 256 blocks = 1/CU). 64 q-rows per tile (16/wave), K-tiles of 64.
// Swizzled V^T staging + register prefetch of next K/V tile.
// ---------------------------------------------------------------------------
__global__ __launch_bounds__(256, 2) void attn_kernel(
    const u16* __restrict__ Q,    // [4096, 1536] (8 heads, pre-scaled)
    const u16* __restrict__ KVB,  // [4096, 2048] (8 heads k_nope|v)
    const u16* __restrict__ KPE,  // [4096, 64]
    u16* __restrict__ O,          // [4096, 2048]
    int hbase) {
  constexpr int LK = 200;
  constexpr int LP = 72;
  __shared__ alignas(16) u16 Ks[64 * LK];
  __shared__ alignas(16) u16 Ps[64 * LP];
  __shared__ alignas(16) u16 Vs[128 * LP];  // swizzled V^T

  const int tid = threadIdx.x;
  const int wave = tid >> 6, lane = tid & 63;
  const int quad = lane >> 4, l16 = lane & 15;
  const int hl = blockIdx.y;
  const size_t tok0 = (size_t)blockIdx.z * SEQ;

  auto process = [&](int qt) {
    const int q0 = qt * 64;
    bf16x8 qf[6];
    {
      const u16* qp = Q + (tok0 + q0 + wave * 16 + l16) * 1536 + hl * 192 + quad * 8;
#pragma unroll
      for (int c = 0; c < 6; ++c) qf[c] = *(const bf16x8*)(qp + c * 32);
    }

    f32x4 o_acc[8] = {};
    float m_i[4], l_i[4];
#pragma unroll
    for (int r = 0; r < 4; ++r) { m_i[r] = NEGBIG; l_i[r] = 0.f; }

    const int nkt = qt + 1;
    uint4 kreg[6], vreg[4];
    auto load_tile = [&](int kt) {
      int k0 = kt * 64;
#pragma unroll
      for (int p = 0; p < 6; ++p) {
        int flat = tid + p * 256;
        int r = flat / 24, c8 = (flat % 24) * 8;
        const u16* src = (c8 < 128)
            ? (KVB + (tok0 + k0 + r) * 2048 + hl * 256 + c8)
            : (KPE + (tok0 + k0 + r) * 64 + (c8 - 128));
        kreg[p] = *(const uint4*)src;
      }
#pragma unroll
      for (int p = 0; p < 4; ++p) {
        int flat = tid + p * 256;
        int r = flat / 16, c8 = (flat % 16) * 8;
        vreg[p] = *(const uint4*)(KVB + (tok0 + k0 + r) * 2048 + hl * 256 + 128 + c8);
      }
    };

    load_tile(0);
    for (int kt = 0; kt < nkt; ++kt) {
      const int k0 = kt * 64;
      __syncthreads();  // previous LDS readers done
#pragma unroll
      for (int p = 0; p < 6; ++p) {
        int flat = tid + p * 256;
        int r = flat / 24, c8 = (flat % 24) * 8;
        *(uint4*)(&Ks[r * LK + c8]) = kreg[p];
      }
#pragma unroll
      for (int p = 0; p < 4; ++p) {
        int flat = tid + p * 256;
        int r = flat / 16, c8 = (flat % 16) * 8;
        union { uint4 v4; u16 e[8]; } t;
        t.v4 = vreg[p];
        int rs = r >> 3, rl = r & 7;
#pragma unroll
        for (int j = 0; j < 8; ++j) {
          int n = c8 + j;
          Vs[n * LP + ((rs ^ ((n >> 3) & 7)) << 3) + rl] = t.e[j];
        }
      }
      __syncthreads();
      if (kt + 1 < nkt) load_tile(kt + 1);

      // scores: 16(q) x 64(k) per wave (Q pre-scaled)
      f32x4 sc[4];
#pragma unroll
      for (int ni = 0; ni < 4; ++ni) {
        f32x4 a = {};
#pragma unroll
        for (int c = 0; c < 6; ++c) {
          bf16x8 kf = *(const bf16x8*)(&Ks[(ni * 16 + l16) * LK + c * 32 + quad * 8]);
          a = __builtin_amdgcn_mfma_f32_16x16x32_bf16(qf[c], kf, a, 0, 0, 0);
        }
        sc[ni] = a;
      }

      const int qrow_base = q0 + wave * 16 + quad * 4;
      if (kt == nkt - 1) {  // only the diagonal tile needs the causal mask
#pragma unroll
        for (int ni = 0; ni < 4; ++ni) {
          int col = k0 + ni * 16 + l16;
#pragma unroll
          for (int r = 0; r < 4; ++r)
            if (col > qrow_base + r) sc[ni][r] = NEGBIG;
        }
      }

      float mloc[4];
#pragma unroll
      for (int r = 0; r < 4; ++r) mloc[r] = NEGBIG;
#pragma unroll
      for (int ni = 0; ni < 4; ++ni)
#pragma unroll
        for (int r = 0; r < 4; ++r) mloc[r] = fmaxf(mloc[r], sc[ni][r]);
#pragma unroll
      for (int off = 1; off < 16; off <<= 1)
#pragma unroll
        for (int r = 0; r < 4; ++r) mloc[r] = fmaxf(mloc[r], __shfl_xor(mloc[r], off, 64));

      float alpha[4], rsum[4];
#pragma unroll
      for (int r = 0; r < 4; ++r) {
        float mn = fmaxf(m_i[r], mloc[r]);
        alpha[r] = __expf(m_i[r] - mn);
        m_i[r] = mn;
        rsum[r] = 0.f;
      }
#pragma unroll
      for (int ni = 0; ni < 4; ++ni)
#pragma unroll
        for (int r = 0; r < 4; ++r) {
          float p = __expf(sc[ni][r] - m_i[r]);
          sc[ni][r] = p;
          rsum[r] += p;
        }
#pragma unroll
      for (int off = 1; off < 16; off <<= 1)
#pragma unroll
        for (int r = 0; r < 4; ++r) rsum[r] += __shfl_xor(rsum[r], off, 64);
#pragma unroll
      for (int r = 0; r < 4; ++r) l_i[r] = l_i[r] * alpha[r] + rsum[r];

#pragma unroll
      for (int ni = 0; ni < 4; ++ni)
#pragma unroll
        for (int r = 0; r < 4; ++r)
          Ps[(wave * 16 + quad * 4 + r) * LP + ni * 16 + l16] = f2b(sc[ni][r]);

      __syncthreads();  // fence: u16 P-writes ordered before bf16x8 P-reads

#pragma unroll
      for (int t8 = 0; t8 < 8; ++t8)
#pragma unroll
        for (int r = 0; r < 4; ++r) o_acc[t8][r] *= alpha[r];

      bf16x8 pf0 = *(const bf16x8*)(&Ps[(wave * 16 + l16) * LP + quad * 8]);
      bf16x8 pf1 = *(const bf16x8*)(&Ps[(wave * 16 + l16) * LP + 32 + quad * 8]);
#pragma unroll
      for (int ni = 0; ni < 8; ++ni) {
        int n0 = ni * 16 + l16;
        int sw = (n0 >> 3) & 7;
        bf16x8 vf0 = *(const bf16x8*)(&Vs[n0 * LP + ((quad ^ sw) << 3)]);
        bf16x8 vf1 = *(const bf16x8*)(&Vs[n0 * LP + (((4 + quad) ^ sw) << 3)]);
        o_acc[ni] = __builtin_amdgcn_mfma_f32_16x16x32_bf16(pf0, vf0, o_acc[ni], 0, 0, 0);
        o_acc[ni] = __builtin_amdgcn_mfma_f32_16x16x32_bf16(pf1, vf1, o_acc[ni], 0, 0, 0);
      }
    }

#pragma unroll
    for (int ni = 0; ni < 8; ++ni) {
      int col = (hbase + hl) * 128 + ni * 16 + l16;
#pragma unroll
      for (int r = 0; r < 4; ++r) {
        size_t row = tok0 + q0 + wave * 16 + quad * 4 + r;
        O[row * 2048 + col] = f2b(o_acc[ni][r] / l_i[r]);
      }
    }
  };

  process(blockIdx.x);        // qt in [0,16): 1..16 K-tiles
  process(31 - blockIdx.x);   // qt in [16,32): 17..32 K-tiles  (total 33)
}

// ---------------------------------------------------------------------------
extern "C" void kernel_launch(void* const* d_in, const int* in_sizes, int n_in,
                              void* d_out, int out_size, void* d_ws, size_t ws_size,
                              hipStream_t stream) {
  const float* x      = (const float*)d_in[0];
  const float* fcos   = (const float*)d_in[1];
  const float* fsin   = (const float*)d_in[2];
  const float* wqa    = (const float*)d_in[3];
  const float* wqa_b  = (const float*)d_in[4];
  const float* qnw    = (const float*)d_in[5];
  const float* wqb    = (const float*)d_in[6];
  const float* wqb_b  = (const float*)d_in[7];
  const float* wkva   = (const float*)d_in[8];
  const float* wkva_b = (const float*)d_in[9];
  const float* kvnw   = (const float*)d_in[10];
  const float* wkvb   = (const float*)d_in[11];
  const float* wkvb_b = (const float*)d_in[12];
  const float* wo     = (const float*)d_in[13];
  const float* wo_b   = (const float*)d_in[14];

  char* ws = (char*)d_ws;
  u16* qn   = (u16*)(ws + 0);           // [4096,1536]
  u16* kvn  = (u16*)(ws + 12582912);    // [4096,576]
  u16* kpe  = (u16*)(ws + 17301504);    // [4096,64]
  u16* qb   = (u16*)(ws + 17825792);    // [4096,1536] (8 heads)
  u16* kvbb = (u16*)(ws + 30408704);    // [4096,2048] (8 heads)
  u16* ao   = (u16*)(ws + 47185920);    // [4096,2048]

  dim3 blk(256);
  gemm_kernel<1,1,0><<<dim3(32, 12), blk, 0, stream>>>(x, 2048, wqa, wqa_b, qn, 4096, 1536, 2048, 1.0f);
  gemm_kernel<1,1,0><<<dim3(32, 5),  blk, 0, stream>>>(x, 2048, wkva, wkva_b, kvn, 4096, 576, 2048, 1.0f);
  rmsnorm_kernel<<<4096, blk, 0, stream>>>(qn, qnw, 1536, 1536);
  rmsnorm_kernel<<<4096, blk, 0, stream>>>(kvn, kvnw, 512, 576);
  rope_kpe_kernel<<<512, blk, 0, stream>>>(kvn, fcos, fsin, kpe);

  for (int g = 0; g < 2; ++g) {
    const float* wqb_g   = wqb + (size_t)g * 1536 * 1536;
    const float* wqb_bg  = wqb_b + g * 1536;
    const float* wkvb_g  = wkvb + (size_t)g * 2048 * 512;
    const float* wkvb_bg = wkvb_b + g * 2048;
    // q projection (8 heads), SCALE folded into epilogue (rope is linear)
    gemm_kernel<0,1,0><<<dim3(32, 12), blk, 0, stream>>>(qn, 1536, wqb_g, wqb_bg, qb, 4096, 1536, 1536, SCALE);
    rope_q_kernel<<<4096, blk, 0, stream>>>(qb, fcos, fsin);
    gemm_kernel<0,1,0><<<dim3(32, 16), blk, 0, stream>>>(kvn, 576, wkvb_g, wkvb_bg, kvbb, 4096, 2048, 512, 1.0f);
    // both batches, 8 heads, paired q-tiles: 256 uniform blocks
    attn_kernel<<<dim3(16, 8, 2), blk, 0, stream>>>(qb, kvbb, kpe, ao, g * 8);
  }

  gemm_kernel<0,1,1><<<dim3(32, 16), blk, 0, stream>>>(ao, 2048, wo, wo_b, (float*)d_out, 4096, 2048, 2048, 1.0f);
}

// Round 8
// 761.938 us; speedup vs baseline: 1.6623x; 1.3442x over previous
//
#include <hip/hip_runtime.h>

// MLA prefill: B=2, S=2048, DIM=2048, NH=16, Q_LORA=1536, KV_LORA=512,
// NOPE=128, ROPE=64, VHD=128, QK_HD=192.
// I/O dtype: FP32. Internal: bf16 MFMA.
//
// WS high-water 63,963,136 B:
//   qn   @ 0           [4096,1536]
//   kvn  @ 12,582,912  [4096, 576]  (cols 512..575 raw pe)
//   kpe  @ 17,301,504  [4096,  64]
//   qb   @ 17,825,792  [4096,1536]  (8 heads x 192, pre-scaled by SCALE)
//   kvbb @ 30,408,704  [4096,2048]  (8 heads x (k_nope128|v128))
//   ao   @ 47,185,920  [4096,2048]

typedef __bf16 bf16x8 __attribute__((ext_vector_type(8)));
typedef float f32x4 __attribute__((ext_vector_type(4)));
typedef unsigned short u16;

#define SEQ 2048
#define SCALE 0.07216878364870323f  // 192^-0.5
#define NEGBIG -30000.0f            // expf underflows to exactly 0

__device__ __forceinline__ float b2f(u16 u) {
  union { unsigned u; float f; } c; c.u = ((unsigned)u) << 16; return c.f;
}
__device__ __forceinline__ u16 f2b(float f) {  // RNE fp32->bf16
  union { float f; unsigned u; } c; c.f = f;
  unsigned r = (c.u + 0x7fffu + ((c.u >> 16) & 1u)) >> 16;
  return (u16)r;
}
__device__ __forceinline__ uint4 pack8(float4 a, float4 b) {
  union { uint4 v; u16 e[8]; } t;
  t.e[0] = f2b(a.x); t.e[1] = f2b(a.y); t.e[2] = f2b(a.z); t.e[3] = f2b(a.w);
  t.e[4] = f2b(b.x); t.e[5] = f2b(b.y); t.e[6] = f2b(b.z); t.e[7] = f2b(b.w);
  return t.v;
}

// ---------------------------------------------------------------------------
// GEMM: out[M,N] = (X[M,K] @ W[N,K]^T + bias[N]) * oscale
// XF/WF: 1 = fp32 source (convert at LDS store), 0 = bf16. OF: 1 = fp32 out.
// Round-8: 64x128 tile (2x the blocks -> 3-4 blocks/CU; grid was the
// occupancy cap at 17%), waves 1x4 (each 64rows x 32cols, acc 4x2),
// register prefetch of tile k+1 so global latency hides behind MFMA.
// ---------------------------------------------------------------------------
template <int XF, int WF, int OF>
__global__ __launch_bounds__(256, 3) void gemm_kernel(
    const void* __restrict__ X, int lda, const void* __restrict__ W,
    const float* __restrict__ bias, void* __restrict__ out,
    int M, int N, int K, float oscale) {
  constexpr int LDT = 72;
  __shared__ alignas(16) u16 As[64 * LDT];
  __shared__ alignas(16) u16 Bs[128 * LDT];
  const int tid = threadIdx.x;
  const int wave = tid >> 6, lane = tid & 63;
  const int quad = lane >> 4, l16 = lane & 15;
  const int bm = blockIdx.x * 64, bn = blockIdx.y * 128;
  const int wn = wave * 32;
  const int srow = tid >> 3;           // 0..31
  const int scol = (tid & 7) * 8;      // 0..56

  f32x4 acc[4][2] = {};

  // register prefetch buffers (tile k+1)
  float4 pa32[2][2], pb32[4][2];
  uint4  pa16[2],    pb16[4];

  auto load_tile = [&](int k0) {
#pragma unroll
    for (int p = 0; p < 2; ++p) {
      size_t off = (size_t)(bm + srow + p * 32) * lda + k0 + scol;
      if (XF) {
        const float* s = (const float*)X + off;
        pa32[p][0] = *(const float4*)s;
        pa32[p][1] = *(const float4*)(s + 4);
      } else {
        pa16[p] = *(const uint4*)((const u16*)X + off);
      }
    }
#pragma unroll
    for (int p = 0; p < 4; ++p) {
      int n = bn + srow + p * 32;
      size_t off = (size_t)n * K + k0 + scol;
      if (WF) {
        if (n < N) {
          const float* s = (const float*)W + off;
          pb32[p][0] = *(const float4*)s;
          pb32[p][1] = *(const float4*)(s + 4);
        } else {
          pb32[p][0] = make_float4(0.f, 0.f, 0.f, 0.f);
          pb32[p][1] = make_float4(0.f, 0.f, 0.f, 0.f);
        }
      } else {
        if (n < N) pb16[p] = *(const uint4*)((const u16*)W + off);
        else { pb16[p].x = pb16[p].y = pb16[p].z = pb16[p].w = 0u; }
      }
    }
  };

  load_tile(0);
  for (int k0 = 0; k0 < K; k0 += 64) {
    __syncthreads();  // previous iteration's LDS readers done
#pragma unroll
    for (int p = 0; p < 2; ++p) {
      uint4 v;
      if (XF) v = pack8(pa32[p][0], pa32[p][1]); else v = pa16[p];
      *(uint4*)(&As[(srow + p * 32) * LDT + scol]) = v;
    }
#pragma unroll
    for (int p = 0; p < 4; ++p) {
      uint4 v;
      if (WF) v = pack8(pb32[p][0], pb32[p][1]); else v = pb16[p];
      *(uint4*)(&Bs[(srow + p * 32) * LDT + scol]) = v;
    }
    __syncthreads();  // also the compiler fence for the u16->bf16x8 pun
    if (k0 + 64 < K) load_tile(k0 + 64);  // latency hidden by MFMA below

#pragma unroll
    for (int kk = 0; kk < 64; kk += 32) {
      bf16x8 a[4], b[2];
#pragma unroll
      for (int i = 0; i < 4; ++i)
        a[i] = *(const bf16x8*)(&As[(i * 16 + l16) * LDT + kk + quad * 8]);
#pragma unroll
      for (int j = 0; j < 2; ++j)
        b[j] = *(const bf16x8*)(&Bs[(wn + j * 16 + l16) * LDT + kk + quad * 8]);
#pragma unroll
      for (int i = 0; i < 4; ++i)
#pragma unroll
        for (int j = 0; j < 2; ++j)
          acc[i][j] = __builtin_amdgcn_mfma_f32_16x16x32_bf16(a[i], b[j], acc[i][j], 0, 0, 0);
    }
  }

#pragma unroll
  for (int i = 0; i < 4; ++i)
#pragma unroll
    for (int j = 0; j < 2; ++j) {
      int col = bn + wn + j * 16 + l16;
      if (col < N) {
        float bv = bias[col];
#pragma unroll
        for (int r = 0; r < 4; ++r) {
          int row = bm + i * 16 + quad * 4 + r;
          float v = (acc[i][j][r] + bv) * oscale;
          if (OF) ((float*)out)[(size_t)row * N + col] = v;
          else    ((u16*)out)[(size_t)row * N + col] = f2b(v);
        }
      }
    }
}

// ---------------------------------------------------------------------------
__global__ void rmsnorm_kernel(u16* x, const float* __restrict__ w,
                               int C, int stride) {
  size_t base = (size_t)blockIdx.x * stride;
  float s = 0.f;
  for (int c = threadIdx.x; c < C; c += 256) { float v = b2f(x[base + c]); s += v * v; }
#pragma unroll
  for (int off = 32; off > 0; off >>= 1) s += __shfl_xor(s, off, 64);
  __shared__ float red[4];
  if ((threadIdx.x & 63) == 0) red[threadIdx.x >> 6] = s;
  __syncthreads();
  float tot = red[0] + red[1] + red[2] + red[3];
  float scale = rsqrtf(tot / (float)C + 1e-6f);
  for (int c = threadIdx.x; c < C; c += 256)
    x[base + c] = f2b(b2f(x[base + c]) * scale * w[c]);
}

// ---------------------------------------------------------------------------
__global__ void rope_kpe_kernel(const u16* __restrict__ kvn,
                                const float* __restrict__ fcos,
                                const float* __restrict__ fsin,
                                u16* __restrict__ kpe) {
  int idx = blockIdx.x * 256 + threadIdx.x;  // token*32 + i
  int t = idx >> 5, i = idx & 31;
  int s = t & (SEQ - 1);
  float c = fcos[s * 32 + i], sn = fsin[s * 32 + i];
  float xr = b2f(kvn[(size_t)t * 576 + 512 + 2 * i]);
  float xi = b2f(kvn[(size_t)t * 576 + 512 + 2 * i + 1]);
  kpe[(size_t)t * 64 + 2 * i]     = f2b(xr * c - xi * sn);
  kpe[(size_t)t * 64 + 2 * i + 1] = f2b(xr * sn + xi * c);
}

// ---------------------------------------------------------------------------
// In-place rope on q_pe, qb layout [4096 tokens, 8 heads x 192].
// ---------------------------------------------------------------------------
__global__ void rope_q_kernel(u16* q, const float* __restrict__ fcos,
                              const float* __restrict__ fsin) {
  int idx = blockIdx.x * 256 + threadIdx.x;  // t*256 + h*32 + i
  int t = idx >> 8, h = (idx >> 5) & 7, i = idx & 31;
  int s = t & (SEQ - 1);
  float c = fcos[s * 32 + i], sn = fsin[s * 32 + i];
  size_t base = (size_t)t * 1536 + h * 192 + 128 + 2 * i;
  float xr = b2f(q[base]), xi = b2f(q[base + 1]);
  q[base]     = f2b(xr * c - xi * sn);
  q[base + 1] = f2b(xr * sn + xi * c);
}

// ---------------------------------------------------------------------------
// Flash attention (causal). grid (16 pairs, 8 heads, 2 batches) — block i
// processes q-tiles i and 31-i (uniform 33 K-tile iters/block).
// Swizzled V^T staging + register prefetch of next K/V tile.
// ---------------------------------------------------------------------------
__global__ __launch_bounds__(256, 2) void attn_kernel(
    const u16* __restrict__ Q,    // [4096, 1536] (8 heads, pre-scaled)
    const u16* __restrict__ KVB,  // [4096, 2048] (8 heads k_nope|v)
    const u16* __restrict__ KPE,  // [4096, 64]
    u16* __restrict__ O,          // [4096, 2048]
    int hbase) {
  constexpr int LK = 200;
  constexpr int LP = 72;
  __shared__ alignas(16) u16 Ks[64 * LK];
  __shared__ alignas(16) u16 Ps[64 * LP];
  __shared__ alignas(16) u16 Vs[128 * LP];  // swizzled V^T

  const int tid = threadIdx.x;
  const int wave = tid >> 6, lane = tid & 63;
  const int quad = lane >> 4, l16 = lane & 15;
  const int hl = blockIdx.y;
  const size_t tok0 = (size_t)blockIdx.z * SEQ;

  auto process = [&](int qt) {
    const int q0 = qt * 64;
    bf16x8 qf[6];
    {
      const u16* qp = Q + (tok0 + q0 + wave * 16 + l16) * 1536 + hl * 192 + quad * 8;
#pragma unroll
      for (int c = 0; c < 6; ++c) qf[c] = *(const bf16x8*)(qp + c * 32);
    }

    f32x4 o_acc[8] = {};
    float m_i[4], l_i[4];
#pragma unroll
    for (int r = 0; r < 4; ++r) { m_i[r] = NEGBIG; l_i[r] = 0.f; }

    const int nkt = qt + 1;
    uint4 kreg[6], vreg[4];
    auto load_tile = [&](int kt) {
      int k0 = kt * 64;
#pragma unroll
      for (int p = 0; p < 6; ++p) {
        int flat = tid + p * 256;
        int r = flat / 24, c8 = (flat % 24) * 8;
        const u16* src = (c8 < 128)
            ? (KVB + (tok0 + k0 + r) * 2048 + hl * 256 + c8)
            : (KPE + (tok0 + k0 + r) * 64 + (c8 - 128));
        kreg[p] = *(const uint4*)src;
      }
#pragma unroll
      for (int p = 0; p < 4; ++p) {
        int flat = tid + p * 256;
        int r = flat / 16, c8 = (flat % 16) * 8;
        vreg[p] = *(const uint4*)(KVB + (tok0 + k0 + r) * 2048 + hl * 256 + 128 + c8);
      }
    };

    load_tile(0);
    for (int kt = 0; kt < nkt; ++kt) {
      const int k0 = kt * 64;
      __syncthreads();  // previous LDS readers done
#pragma unroll
      for (int p = 0; p < 6; ++p) {
        int flat = tid + p * 256;
        int r = flat / 24, c8 = (flat % 24) * 8;
        *(uint4*)(&Ks[r * LK + c8]) = kreg[p];
      }
#pragma unroll
      for (int p = 0; p < 4; ++p) {
        int flat = tid + p * 256;
        int r = flat / 16, c8 = (flat % 16) * 8;
        union { uint4 v4; u16 e[8]; } t;
        t.v4 = vreg[p];
        int rs = r >> 3, rl = r & 7;
#pragma unroll
        for (int j = 0; j < 8; ++j) {
          int n = c8 + j;
          Vs[n * LP + ((rs ^ ((n >> 3) & 7)) << 3) + rl] = t.e[j];
        }
      }
      __syncthreads();
      if (kt + 1 < nkt) load_tile(kt + 1);

      f32x4 sc[4];
#pragma unroll
      for (int ni = 0; ni < 4; ++ni) {
        f32x4 a = {};
#pragma unroll
        for (int c = 0; c < 6; ++c) {
          bf16x8 kf = *(const bf16x8*)(&Ks[(ni * 16 + l16) * LK + c * 32 + quad * 8]);
          a = __builtin_amdgcn_mfma_f32_16x16x32_bf16(qf[c], kf, a, 0, 0, 0);
        }
        sc[ni] = a;
      }

      const int qrow_base = q0 + wave * 16 + quad * 4;
      if (kt == nkt - 1) {  // only the diagonal tile needs the causal mask
#pragma unroll
        for (int ni = 0; ni < 4; ++ni) {
          int col = k0 + ni * 16 + l16;
#pragma unroll
          for (int r = 0; r < 4; ++r)
            if (col > qrow_base + r) sc[ni][r] = NEGBIG;
        }
      }

      float mloc[4];
#pragma unroll
      for (int r = 0; r < 4; ++r) mloc[r] = NEGBIG;
#pragma unroll
      for (int ni = 0; ni < 4; ++ni)
#pragma unroll
        for (int r = 0; r < 4; ++r) mloc[r] = fmaxf(mloc[r], sc[ni][r]);
#pragma unroll
      for (int off = 1; off < 16; off <<= 1)
#pragma unroll
        for (int r = 0; r < 4; ++r) mloc[r] = fmaxf(mloc[r], __shfl_xor(mloc[r], off, 64));

      float alpha[4], rsum[4];
#pragma unroll
      for (int r = 0; r < 4; ++r) {
        float mn = fmaxf(m_i[r], mloc[r]);
        alpha[r] = __expf(m_i[r] - mn);
        m_i[r] = mn;
        rsum[r] = 0.f;
      }
#pragma unroll
      for (int ni = 0; ni < 4; ++ni)
#pragma unroll
        for (int r = 0; r < 4; ++r) {
          float p = __expf(sc[ni][r] - m_i[r]);
          sc[ni][r] = p;
          rsum[r] += p;
        }
#pragma unroll
      for (int off = 1; off < 16; off <<= 1)
#pragma unroll
        for (int r = 0; r < 4; ++r) rsum[r] += __shfl_xor(rsum[r], off, 64);
#pragma unroll
      for (int r = 0; r < 4; ++r) l_i[r] = l_i[r] * alpha[r] + rsum[r];

#pragma unroll
      for (int ni = 0; ni < 4; ++ni)
#pragma unroll
        for (int r = 0; r < 4; ++r)
          Ps[(wave * 16 + quad * 4 + r) * LP + ni * 16 + l16] = f2b(sc[ni][r]);

      __syncthreads();  // fence: u16 P-writes ordered before bf16x8 P-reads

#pragma unroll
      for (int t8 = 0; t8 < 8; ++t8)
#pragma unroll
        for (int r = 0; r < 4; ++r) o_acc[t8][r] *= alpha[r];

      bf16x8 pf0 = *(const bf16x8*)(&Ps[(wave * 16 + l16) * LP + quad * 8]);
      bf16x8 pf1 = *(const bf16x8*)(&Ps[(wave * 16 + l16) * LP + 32 + quad * 8]);
#pragma unroll
      for (int ni = 0; ni < 8; ++ni) {
        int n0 = ni * 16 + l16;
        int sw = (n0 >> 3) & 7;
        bf16x8 vf0 = *(const bf16x8*)(&Vs[n0 * LP + ((quad ^ sw) << 3)]);
        bf16x8 vf1 = *(const bf16x8*)(&Vs[n0 * LP + (((4 + quad) ^ sw) << 3)]);
        o_acc[ni] = __builtin_amdgcn_mfma_f32_16x16x32_bf16(pf0, vf0, o_acc[ni], 0, 0, 0);
        o_acc[ni] = __builtin_amdgcn_mfma_f32_16x16x32_bf16(pf1, vf1, o_acc[ni], 0, 0, 0);
      }
    }

#pragma unroll
    for (int ni = 0; ni < 8; ++ni) {
      int col = (hbase + hl) * 128 + ni * 16 + l16;
#pragma unroll
      for (int r = 0; r < 4; ++r) {
        size_t row = tok0 + q0 + wave * 16 + quad * 4 + r;
        O[row * 2048 + col] = f2b(o_acc[ni][r] / l_i[r]);
      }
    }
  };

  process(blockIdx.x);        // qt in [0,16): 1..16 K-tiles
  process(31 - blockIdx.x);   // qt in [16,32): 17..32 K-tiles  (total 33)
}

// ---------------------------------------------------------------------------
extern "C" void kernel_launch(void* const* d_in, const int* in_sizes, int n_in,
                              void* d_out, int out_size, void* d_ws, size_t ws_size,
                              hipStream_t stream) {
  const float* x      = (const float*)d_in[0];
  const float* fcos   = (const float*)d_in[1];
  const float* fsin   = (const float*)d_in[2];
  const float* wqa    = (const float*)d_in[3];
  const float* wqa_b  = (const float*)d_in[4];
  const float* qnw    = (const float*)d_in[5];
  const float* wqb    = (const float*)d_in[6];
  const float* wqb_b  = (const float*)d_in[7];
  const float* wkva   = (const float*)d_in[8];
  const float* wkva_b = (const float*)d_in[9];
  const float* kvnw   = (const float*)d_in[10];
  const float* wkvb   = (const float*)d_in[11];
  const float* wkvb_b = (const float*)d_in[12];
  const float* wo     = (const float*)d_in[13];
  const float* wo_b   = (const float*)d_in[14];

  char* ws = (char*)d_ws;
  u16* qn   = (u16*)(ws + 0);           // [4096,1536]
  u16* kvn  = (u16*)(ws + 12582912);    // [4096,576]
  u16* kpe  = (u16*)(ws + 17301504);    // [4096,64]
  u16* qb   = (u16*)(ws + 17825792);    // [4096,1536] (8 heads)
  u16* kvbb = (u16*)(ws + 30408704);    // [4096,2048] (8 heads)
  u16* ao   = (u16*)(ws + 47185920);    // [4096,2048]

  dim3 blk(256);
  gemm_kernel<1,1,0><<<dim3(64, 12), blk, 0, stream>>>(x, 2048, wqa, wqa_b, qn, 4096, 1536, 2048, 1.0f);
  gemm_kernel<1,1,0><<<dim3(64, 5),  blk, 0, stream>>>(x, 2048, wkva, wkva_b, kvn, 4096, 576, 2048, 1.0f);
  rmsnorm_kernel<<<4096, blk, 0, stream>>>(qn, qnw, 1536, 1536);
  rmsnorm_kernel<<<4096, blk, 0, stream>>>(kvn, kvnw, 512, 576);
  rope_kpe_kernel<<<512, blk, 0, stream>>>(kvn, fcos, fsin, kpe);

  for (int g = 0; g < 2; ++g) {
    const float* wqb_g   = wqb + (size_t)g * 1536 * 1536;
    const float* wqb_bg  = wqb_b + g * 1536;
    const float* wkvb_g  = wkvb + (size_t)g * 2048 * 512;
    const float* wkvb_bg = wkvb_b + g * 2048;
    // q projection (8 heads), SCALE folded into epilogue (rope is linear)
    gemm_kernel<0,1,0><<<dim3(64, 12), blk, 0, stream>>>(qn, 1536, wqb_g, wqb_bg, qb, 4096, 1536, 1536, SCALE);
    rope_q_kernel<<<4096, blk, 0, stream>>>(qb, fcos, fsin);
    gemm_kernel<0,1,0><<<dim3(64, 16), blk, 0, stream>>>(kvn, 576, wkvb_g, wkvb_bg, kvbb, 4096, 2048, 512, 1.0f);
    // both batches, 8 heads, paired q-tiles: 256 uniform blocks
    attn_kernel<<<dim3(16, 8, 2), blk, 0, stream>>>(qb, kvbb, kpe, ao, g * 8);
  }

  gemm_kernel<0,1,1><<<dim3(64, 16), blk, 0, stream>>>(ao, 2048, wo, wo_b, (float*)d_out, 4096, 2048, 2048, 1.0f);
}